// Round 6
// baseline (218.041 us; speedup 1.0000x reference)
//
#include <hip/hip_runtime.h>

#define NN   1601
#define EMB  300
#define NB   2048
#define L    64
#define TSTR 304   // t0bf row stride (u16)
#define S    72    // LDS matrix stride (u16) -> 144B rows, 16B-aligned frags

typedef __attribute__((ext_vector_type(8))) short bf16x8;
typedef __attribute__((ext_vector_type(4))) float f32x4;

static __device__ __forceinline__ ushort f2b(float x) {
  union { float f; unsigned u; } c; c.f = x;
  unsigned u = c.u;
  return (ushort)((u + 0x7FFFu + ((u >> 16) & 1u)) >> 16);   // RNE
}
static __device__ __forceinline__ float b2f(ushort h) {
  union { unsigned u; float f; } c; c.u = ((unsigned)h) << 16; return c.f;
}

#define LD8(p, r, c) (*(const bf16x8*)&(p)[(size_t)(r) * S + (c)])
#define MFMA(a, bm, acc) __builtin_amdgcn_mfma_f32_16x16x32_bf16((a), (bm), (acc), 0, 0, 0)

// ---------------------------------------------------------------------------
// C = A @ B (300x300x300 f32). Grid (300 rows, 2 col-halves) for occupancy.
// ---------------------------------------------------------------------------
__global__ __launch_bounds__(160) void k_mm_nn(const float* __restrict__ A,
                                               const float* __restrict__ Bm,
                                               float* __restrict__ C) {
  __shared__ float arow[EMB];
  int i = blockIdx.x;
  int h = blockIdx.y;
  for (int k = threadIdx.x; k < EMB; k += 160) arow[k] = A[(size_t)i * EMB + k];
  __syncthreads();
  int j = 150 * h + threadIdx.x;
  if (threadIdx.x < 150) {
    float s0 = 0.f, s1 = 0.f, s2 = 0.f, s3 = 0.f;
    #pragma unroll 2
    for (int k = 0; k < EMB; k += 4) {
      s0 += arow[k + 0] * Bm[(size_t)(k + 0) * EMB + j];
      s1 += arow[k + 1] * Bm[(size_t)(k + 1) * EMB + j];
      s2 += arow[k + 2] * Bm[(size_t)(k + 2) * EMB + j];
      s3 += arow[k + 3] * Bm[(size_t)(k + 3) * EMB + j];
    }
    C[(size_t)i * EMB + j] = (s0 + s1) + (s2 + s3);
  }
}

// ---------------------------------------------------------------------------
// t0bf[n][e] = bf16( sum_k emb[n][k] * Wc[e][k] ), 8 rows x 150-col half
// per block; pads cols 300..303 = 0.
// ---------------------------------------------------------------------------
__global__ __launch_bounds__(160) void k_t0bf(const float* __restrict__ emb,
                                              const float* __restrict__ wc,
                                              ushort* __restrict__ t0bf) {
  __shared__ float4 rows[8][75];
  int n0 = blockIdx.x * 8, tid = threadIdx.x;
  int h = blockIdx.y;
  for (int idx = tid; idx < 8 * EMB; idx += 160) {
    int r = idx / EMB, k = idx - r * EMB;
    int n = n0 + r;
    ((float*)&rows[r][0])[k] = (n < NN) ? emb[(size_t)n * EMB + k] : 0.f;
  }
  __syncthreads();
  int e = 150 * h + tid;
  if (tid < 150) {
    const float4* w4 = (const float4*)wc + (size_t)e * 75;
    float acc[8] = {};
    for (int k4 = 0; k4 < 75; ++k4) {
      float4 wv = w4[k4];
      #pragma unroll
      for (int r = 0; r < 8; ++r) {
        float4 hv = rows[r][k4];
        acc[r] += hv.x * wv.x + hv.y * wv.y + hv.z * wv.z + hv.w * wv.w;
      }
    }
    #pragma unroll
    for (int r = 0; r < 8; ++r) {
      int n = n0 + r;
      if (n < NN) t0bf[(size_t)n * TSTR + e] = f2b(acc[r]);
    }
  } else if (h == 1 && e >= 300 && e < TSTR) {   // zero pad columns 300..303
    #pragma unroll
    for (int r = 0; r < 8; ++r) {
      int n = n0 + r;
      if (n < NN) t0bf[(size_t)n * TSTR + e] = 0;
    }
  }
}

// ---------------------------------------------------------------------------
// Fused per-batch kernel, all-MFMA:
//   A  = norm(gather+I)             (raw in VGPRs, colsum folded into gather)
//   A2 = A*A  via hi/lo bf16 split  (3-term, ~f32 accuracy), stored as A2^T
//   A3 = A*A2 via hi/lo split       -> bf16 row-major
//   out[b]^T-tiles = T0g^T @ A3^T   (operand-swapped MFMA -> float4 stores)
// ---------------------------------------------------------------------------
__global__ __launch_bounds__(256, 4) void k_fused(const int* __restrict__ labels,
                                                  const float* __restrict__ in_adj,
                                                  const ushort* __restrict__ t0bf,
                                                  float* __restrict__ out) {
  __shared__ __align__(16) ushort arena[4 * L * S];   // 36.9 KB
  ushort* Ahi = arena;              // later: Tt chunk (with Alo region)
  ushort* Alo = arena + L * S;
  ushort* AT2 = arena + 2 * L * S;  // AhiT -> A2hiT -> A3b
  ushort* AT3 = arena + 3 * L * S;  // AloT -> A2loT
  __shared__ int   lab[L];
  __shared__ float ps[4][L];
  __shared__ float dv[L];

  int b = blockIdx.x, tid = threadIdx.x;
  int j = tid & 63, g = tid >> 6;
  if (tid < L) lab[tid] = labels[(size_t)b * L + tid];
  __syncthreads();
  int labj = lab[j];

  // gather (raw in regs) + fused column sums
  float raw[16];
  float cs = 0.f;
  #pragma unroll
  for (int q = 0; q < 16; ++q) {
    int i = g + 4 * q;
    float v = in_adj[(size_t)lab[i] * NN + labj];
    v += (i == j) ? 1.f : 0.f;
    raw[q] = v; cs += v;
  }
  ps[g][j] = cs;
  __syncthreads();
  if (tid < L) dv[tid] = 1.f / sqrtf(ps[0][tid] + ps[1][tid] + ps[2][tid] + ps[3][tid]);
  __syncthreads();

  // scale + hi/lo split + direct/transposed stores
  float dj = dv[j];
  #pragma unroll
  for (int q = 0; q < 16; ++q) {
    int i = g + 4 * q;
    float a = raw[q] * dv[i] * dj;
    ushort hi = f2b(a);
    ushort lo = f2b(a - b2f(hi));
    Ahi[(size_t)i * S + j] = hi;
    Alo[(size_t)i * S + j] = lo;
    AT2[(size_t)j * S + i] = hi;
    AT3[(size_t)j * S + i] = lo;
  }
  __syncthreads();

  int lane = tid & 63, w = tid >> 6;
  int lrow = lane & 15, lk = lane >> 4;
  int m0 = 16 * w;

  // A-side fragments of A (rows), reused for A^2 and A^3
  bf16x8 ah0 = LD8(Ahi, m0 + lrow, 8 * lk);
  bf16x8 ah1 = LD8(Ahi, m0 + lrow, 32 + 8 * lk);
  bf16x8 al0 = LD8(Alo, m0 + lrow, 8 * lk);
  bf16x8 al1 = LD8(Alo, m0 + lrow, 32 + 8 * lk);

  // ---- A2 = A @ A  (3-term hi/lo) -> write A2^T into AT2/AT3 ----
  {
    f32x4 acc[4];
    #pragma unroll
    for (int t = 0; t < 4; ++t) {
      f32x4 a = {0.f, 0.f, 0.f, 0.f};
      bf16x8 bh = LD8(AT2, 16 * t + lrow, 8 * lk);
      bf16x8 bl = LD8(AT3, 16 * t + lrow, 8 * lk);
      a = MFMA(ah0, bh, a); a = MFMA(ah0, bl, a); a = MFMA(al0, bh, a);
      bh = LD8(AT2, 16 * t + lrow, 32 + 8 * lk);
      bl = LD8(AT3, 16 * t + lrow, 32 + 8 * lk);
      a = MFMA(ah1, bh, a); a = MFMA(ah1, bl, a); a = MFMA(al1, bh, a);
      acc[t] = a;
    }
    __syncthreads();   // all reads of AT2/AT3 done
    #pragma unroll
    for (int t = 0; t < 4; ++t) {
      ushort4 h4, l4;
      float x;
      x = acc[t][0]; h4.x = f2b(x); l4.x = f2b(x - b2f(h4.x));
      x = acc[t][1]; h4.y = f2b(x); l4.y = f2b(x - b2f(h4.y));
      x = acc[t][2]; h4.z = f2b(x); l4.z = f2b(x - b2f(h4.z));
      x = acc[t][3]; h4.w = f2b(x); l4.w = f2b(x - b2f(h4.w));
      // acc[t][r] = A2[m0+4lk+r][16t+lrow]  ->  A2T[16t+lrow][m0+4lk+r]
      *(ushort4*)&AT2[(size_t)(16 * t + lrow) * S + m0 + 4 * lk] = h4;
      *(ushort4*)&AT3[(size_t)(16 * t + lrow) * S + m0 + 4 * lk] = l4;
    }
  }
  __syncthreads();

  // ---- A3 = A @ A2  (3-term) -> bf16 row-major into AT2 ----
  {
    f32x4 acc[4];
    #pragma unroll
    for (int t = 0; t < 4; ++t) {
      f32x4 a = {0.f, 0.f, 0.f, 0.f};
      bf16x8 bh = LD8(AT2, 16 * t + lrow, 8 * lk);
      bf16x8 bl = LD8(AT3, 16 * t + lrow, 8 * lk);
      a = MFMA(ah0, bh, a); a = MFMA(ah0, bl, a); a = MFMA(al0, bh, a);
      bh = LD8(AT2, 16 * t + lrow, 32 + 8 * lk);
      bl = LD8(AT3, 16 * t + lrow, 32 + 8 * lk);
      a = MFMA(ah1, bh, a); a = MFMA(ah1, bl, a); a = MFMA(al1, bh, a);
      acc[t] = a;
    }
    __syncthreads();   // all reads of AT2/AT3 done
    #pragma unroll
    for (int t = 0; t < 4; ++t)
      #pragma unroll
      for (int r = 0; r < 4; ++r)
        AT2[(size_t)(m0 + 4 * lk + r) * S + 16 * t + lrow] = f2b(acc[t][r]);
  }
  __syncthreads();

  // ---- out^T-tiles = T0g^T @ A3^T  (swapped operands -> float4 row stores)
  // B-side frag: B^T[n=i][k=j] = A3[i][j]  (same reads as before)
  bf16x8 fb0 = LD8(AT2, m0 + lrow, 8 * lk);
  bf16x8 fb1 = LD8(AT2, m0 + lrow, 32 + 8 * lk);
  ushort* Tt = arena;                      // [80][S] max = 5760 u16 < 2*L*S
  const ushort* trow = t0bf + (size_t)labj * TSTR;
  float* orow = out + ((size_t)b * L + m0 + lrow) * EMB;  // this lane's row

  for (int c = 0; c < 4; ++c) {
    int rows80 = (c == 3) ? 64 : 80;
    for (int e = 8 * g; e < rows80; e += 32) {
      union { int4 v; ushort u[8]; } uu;
      uu.v = *(const int4*)(trow + 80 * c + e);
      #pragma unroll
      for (int q = 0; q < 8; ++q) Tt[(size_t)(e + q) * S + j] = uu.u[q];
    }
    __syncthreads();
    int nt = (c == 3) ? 4 : 5;
    for (int t = 0; t < nt; ++t) {
      // A-side frag: A[m=e_local][k=j] = T0g^T chunk rows
      bf16x8 a0 = LD8(Tt, 16 * t + lrow, 8 * lk);
      bf16x8 a1 = LD8(Tt, 16 * t + lrow, 32 + 8 * lk);
      f32x4 o = {0.f, 0.f, 0.f, 0.f};
      o = MFMA(a0, fb0, o);
      o = MFMA(a1, fb1, o);
      // lane holds out[b][m0+lrow][e0 .. e0+3], e0 = 80c+16t+4lk
      int e0 = 80 * c + 16 * t + 4 * lk;
      if (e0 < EMB) {
        __builtin_nontemporal_store(o, (f32x4*)&orow[e0]);
      }
    }
    __syncthreads();
  }
}

// ---------------------------------------------------------------------------
extern "C" void kernel_launch(void* const* d_in, const int* in_sizes, int n_in,
                              void* d_out, int out_size, void* d_ws, size_t ws_size,
                              hipStream_t stream) {
  (void)in_sizes; (void)n_in; (void)out_size; (void)ws_size;
  const int*   labels = (const int*)d_in[0];
  const float* in_adj = (const float*)d_in[1];
  const float* emb    = (const float*)d_in[2];
  const float* lw     = (const float*)d_in[3];
  float* out = (float*)d_out;

  float*  T    = (float*)d_ws;             // 300*300 f32
  float*  Wc   = T + 90000;                // 300*300 f32
  ushort* t0bf = (ushort*)(Wc + 90000);    // 1601*304 bf16

  const float* W1 = lw;
  const float* W2 = lw + (size_t)EMB * EMB;
  const float* W3 = lw + 2 * (size_t)EMB * EMB;

  dim3 gmm(EMB, 2);
  k_mm_nn<<<gmm, 160, 0, stream>>>(W3, W2, T);        // T  = W3@W2
  k_mm_nn<<<gmm, 160, 0, stream>>>(T, W1, Wc);        // Wc = W3@W2@W1
  dim3 gt0((NN + 7) / 8, 2);
  k_t0bf <<<gt0, 160, 0, stream>>>(emb, Wc, t0bf);
  k_fused<<<NB, 256, 0, stream>>>(labels, in_adj, t0bf, out);
}

// Round 7
// 135.172 us; speedup vs baseline: 1.6131x; 1.6131x over previous
//
#include <hip/hip_runtime.h>
#include <hip/hip_fp16.h>

#define NN   1601
#define EMB  300
#define NB   2048
#define L    64
#define TSTR 304   // t0bf / t1 / t2 row stride (elements)
#define S    72    // LDS matrix stride (u16) -> 144B rows, 16B-aligned frags

typedef __attribute__((ext_vector_type(8))) short bf16x8;
typedef __attribute__((ext_vector_type(4))) float f32x4;

static __device__ __forceinline__ ushort f2b(float x) {
  union { float f; unsigned u; } c; c.f = x;
  unsigned u = c.u;
  return (ushort)((u + 0x7FFFu + ((u >> 16) & 1u)) >> 16);   // RNE
}
static __device__ __forceinline__ float b2f(ushort h) {
  union { unsigned u; float f; } c; c.u = ((unsigned)h) << 16; return c.f;
}

#define LD8(p, r, c) (*(const bf16x8*)&(p)[(size_t)(r) * S + (c)])
#define MFMA(a, bm, acc) __builtin_amdgcn_mfma_f32_16x16x32_bf16((a), (bm), (acc), 0, 0, 0)

// ---------------------------------------------------------------------------
// in_adj (f32) -> fp16 table (halves gather HBM lines in k_fused)
// ---------------------------------------------------------------------------
__global__ __launch_bounds__(256) void k_h16(const float* __restrict__ x,
                                             __half* __restrict__ y, int n) {
  for (int i = blockIdx.x * 256 + threadIdx.x; i < n; i += gridDim.x * 256)
    y[i] = __float2half(x[i]);
}

// ---------------------------------------------------------------------------
// C(M x 304) = A(M x K) @ B(300x300)^T  via hi/lo bf16 3-term MFMA (~f32).
// A row-major stride AS, K-guard KG (cols >= KG read as 0).
// C cols 300..303 are written as 0 (B rows >= 300 staged as 0).
// Grid: (ceil(M/64), 5). BF16OUT: C is u16 bf16, else f32. Stride 304.
// ---------------------------------------------------------------------------
template <int BF16OUT>
__global__ __launch_bounds__(256) void k_gemm_bt(const float* __restrict__ A,
                                                 const float* __restrict__ B,
                                                 void* __restrict__ Cout,
                                                 int M, int AS, int KG) {
  __shared__ __align__(16) ushort arena[4 * L * S];   // 36.9 KB
  ushort* Ahi = arena;
  ushort* Alo = arena + L * S;
  ushort* Bhi = arena + 2 * L * S;
  ushort* Blo = arena + 3 * L * S;
  int mb = blockIdx.x, nb = blockIdx.y, tid = threadIdx.x;
  int lane = tid & 63, w = tid >> 6;
  int lrow = lane & 15, lk = lane >> 4;

  f32x4 acc[4];
  #pragma unroll
  for (int t = 0; t < 4; ++t) acc[t] = (f32x4){0.f, 0.f, 0.f, 0.f};

  for (int kc = 0; kc < 5; ++kc) {
    int k0 = 64 * kc;
    for (int idx = tid; idx < 64 * 16; idx += 256) {
      int r = idx >> 4, c4 = (idx & 15) * 4;
      int m = mb * 64 + r, k = k0 + c4;
      float4 v = make_float4(0.f, 0.f, 0.f, 0.f);
      if (m < M && k < KG) v = *(const float4*)&A[(size_t)m * AS + k];
      ushort4 h4, l4;
      h4.x = f2b(v.x); l4.x = f2b(v.x - b2f(h4.x));
      h4.y = f2b(v.y); l4.y = f2b(v.y - b2f(h4.y));
      h4.z = f2b(v.z); l4.z = f2b(v.z - b2f(h4.z));
      h4.w = f2b(v.w); l4.w = f2b(v.w - b2f(h4.w));
      *(ushort4*)&Ahi[r * S + c4] = h4;
      *(ushort4*)&Alo[r * S + c4] = l4;
    }
    for (int idx = tid; idx < 64 * 16; idx += 256) {
      int r = idx >> 4, c4 = (idx & 15) * 4;
      int n = nb * 64 + r, k = k0 + c4;
      float4 v = make_float4(0.f, 0.f, 0.f, 0.f);
      if (n < 300 && k < 300) v = *(const float4*)&B[(size_t)n * 300 + k];
      ushort4 h4, l4;
      h4.x = f2b(v.x); l4.x = f2b(v.x - b2f(h4.x));
      h4.y = f2b(v.y); l4.y = f2b(v.y - b2f(h4.y));
      h4.z = f2b(v.z); l4.z = f2b(v.z - b2f(h4.z));
      h4.w = f2b(v.w); l4.w = f2b(v.w - b2f(h4.w));
      *(ushort4*)&Bhi[r * S + c4] = h4;
      *(ushort4*)&Blo[r * S + c4] = l4;
    }
    __syncthreads();
    #pragma unroll
    for (int ks = 0; ks < 2; ++ks) {
      bf16x8 ah = LD8(Ahi, 16 * w + lrow, 32 * ks + 8 * lk);
      bf16x8 al = LD8(Alo, 16 * w + lrow, 32 * ks + 8 * lk);
      #pragma unroll
      for (int t = 0; t < 4; ++t) {
        bf16x8 bh = LD8(Bhi, 16 * t + lrow, 32 * ks + 8 * lk);
        bf16x8 bl = LD8(Blo, 16 * t + lrow, 32 * ks + 8 * lk);
        acc[t] = MFMA(ah, bh, acc[t]);
        acc[t] = MFMA(ah, bl, acc[t]);
        acc[t] = MFMA(al, bh, acc[t]);
      }
    }
    __syncthreads();
  }
  #pragma unroll
  for (int t = 0; t < 4; ++t) {
    int n = nb * 64 + 16 * t + lrow;
    int mbase = mb * 64 + 16 * w + 4 * lk;
    if (n < TSTR) {
      #pragma unroll
      for (int r = 0; r < 4; ++r) {
        int m = mbase + r;
        if (m < M) {
          if (BF16OUT) ((ushort*)Cout)[(size_t)m * TSTR + n] = f2b(acc[t][r]);
          else         ((float*)Cout)[(size_t)m * TSTR + n] = acc[t][r];
        }
      }
    }
  }
}

// ---------------------------------------------------------------------------
// Fused per-batch kernel, all-MFMA:
//   A  = norm(gather_fp16 + I)      (raw in VGPRs, colsum folded into gather)
//   A2 = A*A  via hi/lo bf16 split  (3-term, ~f32 accuracy), stored as A2^T
//   A3 = A*A2 via hi/lo split       -> bf16 row-major
//   out[b]^T-tiles = T0g^T @ A3^T   (operand-swapped MFMA -> float4 stores)
// ---------------------------------------------------------------------------
__global__ __launch_bounds__(256, 4) void k_fused(const int* __restrict__ labels,
                                                  const __half* __restrict__ adj16,
                                                  const ushort* __restrict__ t0bf,
                                                  float* __restrict__ out) {
  __shared__ __align__(16) ushort arena[4 * L * S];   // 36.9 KB
  ushort* Ahi = arena;              // later: Tt chunk (with Alo region)
  ushort* Alo = arena + L * S;
  ushort* AT2 = arena + 2 * L * S;  // AhiT -> A2hiT -> A3b
  ushort* AT3 = arena + 3 * L * S;  // AloT -> A2loT
  __shared__ int   lab[L];
  __shared__ float ps[4][L];
  __shared__ float dv[L];

  int b = blockIdx.x, tid = threadIdx.x;
  int j = tid & 63, g = tid >> 6;
  if (tid < L) lab[tid] = labels[(size_t)b * L + tid];
  __syncthreads();
  int labj = lab[j];

  // gather (raw in regs) + fused column sums
  float raw[16];
  float cs = 0.f;
  #pragma unroll
  for (int q = 0; q < 16; ++q) {
    int i = g + 4 * q;
    float v = __half2float(adj16[(size_t)lab[i] * NN + labj]);
    v += (i == j) ? 1.f : 0.f;
    raw[q] = v; cs += v;
  }
  ps[g][j] = cs;
  __syncthreads();
  if (tid < L) dv[tid] = 1.f / sqrtf(ps[0][tid] + ps[1][tid] + ps[2][tid] + ps[3][tid]);
  __syncthreads();

  // scale + hi/lo split + direct/transposed stores
  float dj = dv[j];
  #pragma unroll
  for (int q = 0; q < 16; ++q) {
    int i = g + 4 * q;
    float a = raw[q] * dv[i] * dj;
    ushort hi = f2b(a);
    ushort lo = f2b(a - b2f(hi));
    Ahi[(size_t)i * S + j] = hi;
    Alo[(size_t)i * S + j] = lo;
    AT2[(size_t)j * S + i] = hi;
    AT3[(size_t)j * S + i] = lo;
  }
  __syncthreads();

  int lane = tid & 63, w = tid >> 6;
  int lrow = lane & 15, lk = lane >> 4;
  int m0 = 16 * w;

  // A-side fragments of A (rows), reused for A^2 and A^3
  bf16x8 ah0 = LD8(Ahi, m0 + lrow, 8 * lk);
  bf16x8 ah1 = LD8(Ahi, m0 + lrow, 32 + 8 * lk);
  bf16x8 al0 = LD8(Alo, m0 + lrow, 8 * lk);
  bf16x8 al1 = LD8(Alo, m0 + lrow, 32 + 8 * lk);

  // ---- A2 = A @ A  (3-term hi/lo) -> write A2^T into AT2/AT3 ----
  {
    f32x4 acc[4];
    #pragma unroll
    for (int t = 0; t < 4; ++t) {
      f32x4 a = {0.f, 0.f, 0.f, 0.f};
      bf16x8 bh = LD8(AT2, 16 * t + lrow, 8 * lk);
      bf16x8 bl = LD8(AT3, 16 * t + lrow, 8 * lk);
      a = MFMA(ah0, bh, a); a = MFMA(ah0, bl, a); a = MFMA(al0, bh, a);
      bh = LD8(AT2, 16 * t + lrow, 32 + 8 * lk);
      bl = LD8(AT3, 16 * t + lrow, 32 + 8 * lk);
      a = MFMA(ah1, bh, a); a = MFMA(ah1, bl, a); a = MFMA(al1, bh, a);
      acc[t] = a;
    }
    __syncthreads();   // all reads of AT2/AT3 done
    #pragma unroll
    for (int t = 0; t < 4; ++t) {
      ushort4 h4, l4;
      float x;
      x = acc[t][0]; h4.x = f2b(x); l4.x = f2b(x - b2f(h4.x));
      x = acc[t][1]; h4.y = f2b(x); l4.y = f2b(x - b2f(h4.y));
      x = acc[t][2]; h4.z = f2b(x); l4.z = f2b(x - b2f(h4.z));
      x = acc[t][3]; h4.w = f2b(x); l4.w = f2b(x - b2f(h4.w));
      // acc[t][r] = A2[m0+4lk+r][16t+lrow]  ->  A2T[16t+lrow][m0+4lk+r]
      *(ushort4*)&AT2[(size_t)(16 * t + lrow) * S + m0 + 4 * lk] = h4;
      *(ushort4*)&AT3[(size_t)(16 * t + lrow) * S + m0 + 4 * lk] = l4;
    }
  }
  __syncthreads();

  // ---- A3 = A @ A2  (3-term) -> bf16 row-major into AT2 ----
  {
    f32x4 acc[4];
    #pragma unroll
    for (int t = 0; t < 4; ++t) {
      f32x4 a = {0.f, 0.f, 0.f, 0.f};
      bf16x8 bh = LD8(AT2, 16 * t + lrow, 8 * lk);
      bf16x8 bl = LD8(AT3, 16 * t + lrow, 8 * lk);
      a = MFMA(ah0, bh, a); a = MFMA(ah0, bl, a); a = MFMA(al0, bh, a);
      bh = LD8(AT2, 16 * t + lrow, 32 + 8 * lk);
      bl = LD8(AT3, 16 * t + lrow, 32 + 8 * lk);
      a = MFMA(ah1, bh, a); a = MFMA(ah1, bl, a); a = MFMA(al1, bh, a);
      acc[t] = a;
    }
    __syncthreads();   // all reads of AT2/AT3 done
    #pragma unroll
    for (int t = 0; t < 4; ++t)
      #pragma unroll
      for (int r = 0; r < 4; ++r)
        AT2[(size_t)(m0 + 4 * lk + r) * S + 16 * t + lrow] = f2b(acc[t][r]);
  }
  __syncthreads();

  // ---- out^T-tiles = T0g^T @ A3^T  (swapped operands -> float4 row stores)
  bf16x8 fb0 = LD8(AT2, m0 + lrow, 8 * lk);
  bf16x8 fb1 = LD8(AT2, m0 + lrow, 32 + 8 * lk);
  ushort* Tt = arena;                      // [80][S] max = 5760 u16 < 2*L*S
  const ushort* trow = t0bf + (size_t)labj * TSTR;
  float* orow = out + ((size_t)b * L + m0 + lrow) * EMB;  // this lane's row

  for (int c = 0; c < 4; ++c) {
    int rows80 = (c == 3) ? 64 : 80;
    for (int e = 8 * g; e < rows80; e += 32) {
      union { int4 v; ushort u[8]; } uu;
      uu.v = *(const int4*)(trow + 80 * c + e);
      #pragma unroll
      for (int q = 0; q < 8; ++q) Tt[(size_t)(e + q) * S + j] = uu.u[q];
    }
    __syncthreads();
    int nt = (c == 3) ? 4 : 5;
    for (int t = 0; t < nt; ++t) {
      bf16x8 a0 = LD8(Tt, 16 * t + lrow, 8 * lk);
      bf16x8 a1 = LD8(Tt, 16 * t + lrow, 32 + 8 * lk);
      f32x4 o = {0.f, 0.f, 0.f, 0.f};
      o = MFMA(a0, fb0, o);
      o = MFMA(a1, fb1, o);
      // lane holds out[b][m0+lrow][e0 .. e0+3], e0 = 80c+16t+4lk
      int e0 = 80 * c + 16 * t + 4 * lk;
      if (e0 < EMB) {
        *(f32x4*)&orow[e0] = o;
      }
    }
    __syncthreads();
  }
}

// ---------------------------------------------------------------------------
extern "C" void kernel_launch(void* const* d_in, const int* in_sizes, int n_in,
                              void* d_out, int out_size, void* d_ws, size_t ws_size,
                              hipStream_t stream) {
  (void)in_sizes; (void)n_in; (void)out_size; (void)ws_size;
  const int*   labels = (const int*)d_in[0];
  const float* in_adj = (const float*)d_in[1];
  const float* emb    = (const float*)d_in[2];
  const float* lw     = (const float*)d_in[3];
  float* out = (float*)d_out;

  char* base = (char*)d_ws;
  __half* adj16 = (__half*)base;                               // 5.13 MB
  float*  t1    = (float*)(base + 5130240);                    // 1601x304 f32
  float*  t2    = (float*)(base + 5130240 + 1946816);          // 1601x304 f32
  ushort* t0bf  = (ushort*)(base + 5130240 + 2 * 1946816);     // 1601x304 bf16

  const float* W1 = lw;
  const float* W2 = lw + (size_t)EMB * EMB;
  const float* W3 = lw + 2 * (size_t)EMB * EMB;

  k_h16<<<2048, 256, 0, stream>>>(in_adj, adj16, NN * NN);

  dim3 gg((NN + 63) / 64, 5);
  k_gemm_bt<0><<<gg, 256, 0, stream>>>(emb, W1, t1, NN, 300, 300);   // t1 = emb@W1^T
  k_gemm_bt<0><<<gg, 256, 0, stream>>>(t1, W2, t2, NN, TSTR, TSTR);  // t2 = t1@W2^T
  k_gemm_bt<1><<<gg, 256, 0, stream>>>(t2, W3, t0bf, NN, TSTR, TSTR);// t0 = t2@W3^T (bf16)

  k_fused<<<NB, 256, 0, stream>>>(labels, adj16, t0bf, out);
}

// Round 8
// 122.837 us; speedup vs baseline: 1.7750x; 1.1004x over previous
//
#include <hip/hip_runtime.h>

#define NN   1601
#define EMB  300
#define NB   2048
#define L    64
#define TSTR 304   // t0bf / T / Wc row stride (elements)
#define S    72    // LDS matrix stride (u16) -> 144B rows, 16B-aligned frags

typedef __attribute__((ext_vector_type(8))) short bf16x8;
typedef __attribute__((ext_vector_type(4))) float f32x4;

static __device__ __forceinline__ ushort f2b(float x) {
  union { float f; unsigned u; } c; c.f = x;
  unsigned u = c.u;
  return (ushort)((u + 0x7FFFu + ((u >> 16) & 1u)) >> 16);   // RNE
}
static __device__ __forceinline__ float b2f(ushort h) {
  union { unsigned u; float f; } c; c.u = ((unsigned)h) << 16; return c.f;
}

#define LD8(p, r, c) (*(const bf16x8*)&(p)[(size_t)(r) * S + (c)])
#define MFMA(a, bm, acc) __builtin_amdgcn_mfma_f32_16x16x32_bf16((a), (bm), (acc), 0, 0, 0)

// ---------------------------------------------------------------------------
// in_adj (f32 in [0,1)) -> u8 fixed point (q = round(255 v)). 2.56 MB table
// fits per-XCD L2 -> gather in k_fused becomes L2-resident.
// ---------------------------------------------------------------------------
__global__ __launch_bounds__(256) void k_u8(const float* __restrict__ x,
                                            unsigned char* __restrict__ y) {
  const int total = NN * NN;           // 2563201
  const int n4 = total >> 2;           // 640800
  int i = blockIdx.x * 256 + threadIdx.x;
  for (int i4 = i; i4 < n4; i4 += gridDim.x * 256) {
    float4 v = *(const float4*)&x[4 * i4];
    uchar4 q;
    q.x = (unsigned char)__float2int_rn(v.x * 255.f);
    q.y = (unsigned char)__float2int_rn(v.y * 255.f);
    q.z = (unsigned char)__float2int_rn(v.z * 255.f);
    q.w = (unsigned char)__float2int_rn(v.w * 255.f);
    *(uchar4*)&y[4 * i4] = q;
  }
  if (i == 0)                          // tail (total % 4 == 1)
    y[total - 1] = (unsigned char)__float2int_rn(x[total - 1] * 255.f);
}

// ---------------------------------------------------------------------------
// C(. x 304-stride) = A @ B^T (BT=1) or A @ B (BT=0), via hi/lo bf16 3-term
// MFMA (~f32 accuracy). A: M x ~K row-major stride AS, guard KG.
// B: 300x300 f32 row-major stride BS. C: stride TSTR, cols >=300 get 0.
// Grid: (ceil(M/64), 5).
// ---------------------------------------------------------------------------
template <int BT, int BF16OUT>
__global__ __launch_bounds__(256) void k_gemm(const float* __restrict__ A,
                                              const float* __restrict__ B,
                                              void* __restrict__ Cout,
                                              int M, int AS, int BS, int KG) {
  __shared__ __align__(16) ushort arena[4 * L * S];   // 36.9 KB
  ushort* Ahi = arena;
  ushort* Alo = arena + L * S;
  ushort* Bhi = arena + 2 * L * S;
  ushort* Blo = arena + 3 * L * S;
  int mb = blockIdx.x, nb = blockIdx.y, tid = threadIdx.x;
  int lane = tid & 63, w = tid >> 6;
  int lrow = lane & 15, lk = lane >> 4;

  f32x4 acc[4];
  #pragma unroll
  for (int t = 0; t < 4; ++t) acc[t] = (f32x4){0.f, 0.f, 0.f, 0.f};

  for (int kc = 0; kc < 5; ++kc) {
    int k0 = 64 * kc;
    // stage A rows (hi/lo)
    for (int idx = tid; idx < 64 * 16; idx += 256) {
      int r = idx >> 4, c4 = (idx & 15) * 4;
      int m = mb * 64 + r, k = k0 + c4;
      float4 v = make_float4(0.f, 0.f, 0.f, 0.f);
      if (m < M && k < KG) v = *(const float4*)&A[(size_t)m * AS + k];
      ushort4 h4, l4;
      h4.x = f2b(v.x); l4.x = f2b(v.x - b2f(h4.x));
      h4.y = f2b(v.y); l4.y = f2b(v.y - b2f(h4.y));
      h4.z = f2b(v.z); l4.z = f2b(v.z - b2f(h4.z));
      h4.w = f2b(v.w); l4.w = f2b(v.w - b2f(h4.w));
      *(ushort4*)&Ahi[r * S + c4] = h4;
      *(ushort4*)&Alo[r * S + c4] = l4;
    }
    // stage B: frag[n_local][k_local] = (BT ? B[n][k] : B[k][n])
    for (int idx = tid; idx < 64 * 16; idx += 256) {
      int r = idx >> 4, c4 = (idx & 15) * 4;
      if (BT) {
        int n = nb * 64 + r, k = k0 + c4;
        float4 v = make_float4(0.f, 0.f, 0.f, 0.f);
        if (n < 300 && k < 300) v = *(const float4*)&B[(size_t)n * BS + k];
        ushort4 h4, l4;
        h4.x = f2b(v.x); l4.x = f2b(v.x - b2f(h4.x));
        h4.y = f2b(v.y); l4.y = f2b(v.y - b2f(h4.y));
        h4.z = f2b(v.z); l4.z = f2b(v.z - b2f(h4.z));
        h4.w = f2b(v.w); l4.w = f2b(v.w - b2f(h4.w));
        *(ushort4*)&Bhi[r * S + c4] = h4;
        *(ushort4*)&Blo[r * S + c4] = l4;
      } else {
        int k = k0 + r, n = nb * 64 + c4;
        float4 v = make_float4(0.f, 0.f, 0.f, 0.f);
        if (k < 300 && n < 300) v = *(const float4*)&B[(size_t)k * BS + n];
        #pragma unroll
        for (int q = 0; q < 4; ++q) {
          float xq = (q == 0) ? v.x : (q == 1) ? v.y : (q == 2) ? v.z : v.w;
          ushort hi = f2b(xq);
          Bhi[(size_t)(c4 + q) * S + r] = hi;
          Blo[(size_t)(c4 + q) * S + r] = f2b(xq - b2f(hi));
        }
      }
    }
    __syncthreads();
    #pragma unroll
    for (int ks = 0; ks < 2; ++ks) {
      bf16x8 ah = LD8(Ahi, 16 * w + lrow, 32 * ks + 8 * lk);
      bf16x8 al = LD8(Alo, 16 * w + lrow, 32 * ks + 8 * lk);
      #pragma unroll
      for (int t = 0; t < 4; ++t) {
        bf16x8 bh = LD8(Bhi, 16 * t + lrow, 32 * ks + 8 * lk);
        bf16x8 bl = LD8(Blo, 16 * t + lrow, 32 * ks + 8 * lk);
        acc[t] = MFMA(ah, bh, acc[t]);
        acc[t] = MFMA(ah, bl, acc[t]);
        acc[t] = MFMA(al, bh, acc[t]);
      }
    }
    __syncthreads();
  }
  #pragma unroll
  for (int t = 0; t < 4; ++t) {
    int n = nb * 64 + 16 * t + lrow;
    int mbase = mb * 64 + 16 * w + 4 * lk;
    if (n < TSTR) {
      #pragma unroll
      for (int r = 0; r < 4; ++r) {
        int m = mbase + r;
        if (m < M) {
          if (BF16OUT) ((ushort*)Cout)[(size_t)m * TSTR + n] = f2b(acc[t][r]);
          else         ((float*)Cout)[(size_t)m * TSTR + n] = acc[t][r];
        }
      }
    }
  }
}

// ---------------------------------------------------------------------------
// Fused per-batch kernel, all-MFMA:
//   A  = norm(gather_u8 + I)        (255-scale cancels in normalization)
//   A2 = A*A  via hi/lo bf16 split  (3-term, ~f32 accuracy), stored as A2^T
//   A3 = A*A2 via hi/lo split       -> bf16 row-major
//   out[b]^T-tiles = T0g^T @ A3^T   (operand-swapped MFMA -> float4 stores)
// ---------------------------------------------------------------------------
__global__ __launch_bounds__(256, 4) void k_fused(const int* __restrict__ labels,
                                                  const unsigned char* __restrict__ adj8,
                                                  const ushort* __restrict__ t0bf,
                                                  float* __restrict__ out) {
  __shared__ __align__(16) ushort arena[4 * L * S];   // 36.9 KB
  ushort* Ahi = arena;              // later: Tt chunk (with Alo region)
  ushort* Alo = arena + L * S;
  ushort* AT2 = arena + 2 * L * S;  // AhiT -> A2hiT -> A3b
  ushort* AT3 = arena + 3 * L * S;  // AloT -> A2loT
  __shared__ int   lab[L];
  __shared__ float ps[4][L];
  __shared__ float dv[L];

  int b = blockIdx.x, tid = threadIdx.x;
  int j = tid & 63, g = tid >> 6;
  if (tid < L) lab[tid] = labels[(size_t)b * L + tid];
  __syncthreads();
  int labj = lab[j];

  // gather raw counts (incl. 255*I) + fused column sums
  float raw[16];
  float cs = 0.f;
  #pragma unroll
  for (int q = 0; q < 16; ++q) {
    int i = g + 4 * q;
    float v = (float)adj8[(size_t)lab[i] * NN + labj];
    v += (i == j) ? 255.f : 0.f;
    raw[q] = v; cs += v;
  }
  ps[g][j] = cs;
  __syncthreads();
  if (tid < L) dv[tid] = 1.f / sqrtf(ps[0][tid] + ps[1][tid] + ps[2][tid] + ps[3][tid]);
  __syncthreads();

  // scale + hi/lo split + direct/transposed stores
  float dj = dv[j];
  #pragma unroll
  for (int q = 0; q < 16; ++q) {
    int i = g + 4 * q;
    float a = raw[q] * dv[i] * dj;
    ushort hi = f2b(a);
    ushort lo = f2b(a - b2f(hi));
    Ahi[(size_t)i * S + j] = hi;
    Alo[(size_t)i * S + j] = lo;
    AT2[(size_t)j * S + i] = hi;
    AT3[(size_t)j * S + i] = lo;
  }
  __syncthreads();

  int lane = tid & 63, w = tid >> 6;
  int lrow = lane & 15, lk = lane >> 4;
  int m0 = 16 * w;

  // A-side fragments of A (rows), reused for A^2 and A^3
  bf16x8 ah0 = LD8(Ahi, m0 + lrow, 8 * lk);
  bf16x8 ah1 = LD8(Ahi, m0 + lrow, 32 + 8 * lk);
  bf16x8 al0 = LD8(Alo, m0 + lrow, 8 * lk);
  bf16x8 al1 = LD8(Alo, m0 + lrow, 32 + 8 * lk);

  // ---- A2 = A @ A  (3-term hi/lo) -> write A2^T into AT2/AT3 ----
  {
    f32x4 acc[4];
    #pragma unroll
    for (int t = 0; t < 4; ++t) {
      f32x4 a = {0.f, 0.f, 0.f, 0.f};
      bf16x8 bh = LD8(AT2, 16 * t + lrow, 8 * lk);
      bf16x8 bl = LD8(AT3, 16 * t + lrow, 8 * lk);
      a = MFMA(ah0, bh, a); a = MFMA(ah0, bl, a); a = MFMA(al0, bh, a);
      bh = LD8(AT2, 16 * t + lrow, 32 + 8 * lk);
      bl = LD8(AT3, 16 * t + lrow, 32 + 8 * lk);
      a = MFMA(ah1, bh, a); a = MFMA(ah1, bl, a); a = MFMA(al1, bh, a);
      acc[t] = a;
    }
    __syncthreads();   // all reads of AT2/AT3 done
    #pragma unroll
    for (int t = 0; t < 4; ++t) {
      ushort4 h4, l4;
      float x;
      x = acc[t][0]; h4.x = f2b(x); l4.x = f2b(x - b2f(h4.x));
      x = acc[t][1]; h4.y = f2b(x); l4.y = f2b(x - b2f(h4.y));
      x = acc[t][2]; h4.z = f2b(x); l4.z = f2b(x - b2f(h4.z));
      x = acc[t][3]; h4.w = f2b(x); l4.w = f2b(x - b2f(h4.w));
      // acc[t][r] = A2[m0+4lk+r][16t+lrow]  ->  A2T[16t+lrow][m0+4lk+r]
      *(ushort4*)&AT2[(size_t)(16 * t + lrow) * S + m0 + 4 * lk] = h4;
      *(ushort4*)&AT3[(size_t)(16 * t + lrow) * S + m0 + 4 * lk] = l4;
    }
  }
  __syncthreads();

  // ---- A3 = A @ A2  (3-term) -> bf16 row-major into AT2 ----
  {
    f32x4 acc[4];
    #pragma unroll
    for (int t = 0; t < 4; ++t) {
      f32x4 a = {0.f, 0.f, 0.f, 0.f};
      bf16x8 bh = LD8(AT2, 16 * t + lrow, 8 * lk);
      bf16x8 bl = LD8(AT3, 16 * t + lrow, 8 * lk);
      a = MFMA(ah0, bh, a); a = MFMA(ah0, bl, a); a = MFMA(al0, bh, a);
      bh = LD8(AT2, 16 * t + lrow, 32 + 8 * lk);
      bl = LD8(AT3, 16 * t + lrow, 32 + 8 * lk);
      a = MFMA(ah1, bh, a); a = MFMA(ah1, bl, a); a = MFMA(al1, bh, a);
      acc[t] = a;
    }
    __syncthreads();   // all reads of AT2/AT3 done
    #pragma unroll
    for (int t = 0; t < 4; ++t)
      #pragma unroll
      for (int r = 0; r < 4; ++r)
        AT2[(size_t)(m0 + 4 * lk + r) * S + 16 * t + lrow] = f2b(acc[t][r]);
  }
  __syncthreads();

  // ---- out^T-tiles = T0g^T @ A3^T  (swapped operands -> float4 row stores)
  bf16x8 fb0 = LD8(AT2, m0 + lrow, 8 * lk);
  bf16x8 fb1 = LD8(AT2, m0 + lrow, 32 + 8 * lk);
  ushort* Tt = arena;                      // [80][S] max = 5760 u16 < 2*L*S
  const ushort* trow = t0bf + (size_t)labj * TSTR;
  float* orow = out + ((size_t)b * L + m0 + lrow) * EMB;  // this lane's row

  for (int c = 0; c < 4; ++c) {
    int rows80 = (c == 3) ? 64 : 80;
    for (int e = 8 * g; e < rows80; e += 32) {
      union { int4 v; ushort u[8]; } uu;
      uu.v = *(const int4*)(trow + 80 * c + e);
      #pragma unroll
      for (int q = 0; q < 8; ++q) Tt[(size_t)(e + q) * S + j] = uu.u[q];
    }
    __syncthreads();
    int nt = (c == 3) ? 4 : 5;
    for (int t = 0; t < nt; ++t) {
      bf16x8 a0 = LD8(Tt, 16 * t + lrow, 8 * lk);
      bf16x8 a1 = LD8(Tt, 16 * t + lrow, 32 + 8 * lk);
      f32x4 o = {0.f, 0.f, 0.f, 0.f};
      o = MFMA(a0, fb0, o);
      o = MFMA(a1, fb1, o);
      int e0 = 80 * c + 16 * t + 4 * lk;
      if (e0 < EMB) {
        *(f32x4*)&orow[e0] = o;
      }
    }
    __syncthreads();
  }
}

// ---------------------------------------------------------------------------
extern "C" void kernel_launch(void* const* d_in, const int* in_sizes, int n_in,
                              void* d_out, int out_size, void* d_ws, size_t ws_size,
                              hipStream_t stream) {
  (void)in_sizes; (void)n_in; (void)out_size; (void)ws_size;
  const int*   labels = (const int*)d_in[0];
  const float* in_adj = (const float*)d_in[1];
  const float* emb    = (const float*)d_in[2];
  const float* lw     = (const float*)d_in[3];
  float* out = (float*)d_out;

  char* base = (char*)d_ws;
  unsigned char* adj8 = (unsigned char*)base;            // 2,563,201 B
  float*  T    = (float*)(base + 2563216);               // 300x304 f32
  float*  Wc   = (float*)(base + 2563216 + 364800);      // 300x304 f32
  ushort* t0bf = (ushort*)(base + 2563216 + 729600);     // 1601x304 bf16

  const float* W1 = lw;
  const float* W2 = lw + (size_t)EMB * EMB;
  const float* W3 = lw + 2 * (size_t)EMB * EMB;

  k_u8<<<1024, 256, 0, stream>>>(in_adj, adj8);

  dim3 gsm(5, 5), gbig(26, 5);
  k_gemm<0, 0><<<gsm, 256, 0, stream>>>(W3, W2, T, 300, 300, 300, 300);   // T  = W3@W2
  k_gemm<0, 0><<<gsm, 256, 0, stream>>>(T, W1, Wc, 300, TSTR, 300, 300);  // Wc = T@W1
  k_gemm<1, 1><<<gbig, 256, 0, stream>>>(emb, Wc, t0bf, NN, 300, TSTR, 300); // t0 = emb@Wc^T

  k_fused<<<NB, 256, 0, stream>>>(labels, adj8, t0bf, out);
}

// Round 9
// 117.127 us; speedup vs baseline: 1.8616x; 1.0487x over previous
//
#include <hip/hip_runtime.h>

#define NN   1601
#define EMB  300
#define NB   2048
#define L    64
#define TSTR 304   // t0bf / T / Wc row stride (elements)
#define S    72    // LDS matrix stride (u16) -> 144B rows, 16B-aligned frags

typedef __attribute__((ext_vector_type(8))) short bf16x8;
typedef __attribute__((ext_vector_type(4))) float f32x4;

static __device__ __forceinline__ ushort f2b(float x) {
  union { float f; unsigned u; } c; c.f = x;
  unsigned u = c.u;
  return (ushort)((u + 0x7FFFu + ((u >> 16) & 1u)) >> 16);   // RNE
}
static __device__ __forceinline__ float b2f(ushort h) {
  union { unsigned u; float f; } c; c.u = ((unsigned)h) << 16; return c.f;
}

#define LD8(p, r, c) (*(const bf16x8*)&(p)[(size_t)(r) * S + (c)])
#define MFMA(a, bm, acc) __builtin_amdgcn_mfma_f32_16x16x32_bf16((a), (bm), (acc), 0, 0, 0)

// ---------------------------------------------------------------------------
// in_adj (f32 in [0,1)) -> u8 fixed point (q = round(255 v)). 2.56 MB table
// fits per-XCD L2 -> gather in k_fused is L2-resident.
// ---------------------------------------------------------------------------
__global__ __launch_bounds__(256) void k_u8(const float* __restrict__ x,
                                            unsigned char* __restrict__ y) {
  const int total = NN * NN;           // 2563201
  const int n4 = total >> 2;           // 640800
  int i = blockIdx.x * 256 + threadIdx.x;
  for (int i4 = i; i4 < n4; i4 += gridDim.x * 256) {
    float4 v = *(const float4*)&x[4 * i4];
    uchar4 q;
    q.x = (unsigned char)__float2int_rn(v.x * 255.f);
    q.y = (unsigned char)__float2int_rn(v.y * 255.f);
    q.z = (unsigned char)__float2int_rn(v.z * 255.f);
    q.w = (unsigned char)__float2int_rn(v.w * 255.f);
    *(uchar4*)&y[4 * i4] = q;
  }
  if (i == 0)                          // tail (total % 4 == 1)
    y[total - 1] = (unsigned char)__float2int_rn(x[total - 1] * 255.f);
}

// ---------------------------------------------------------------------------
// C(. x 304-stride) = A @ B^T (BT=1) or A @ B (BT=0), via hi/lo bf16 3-term
// MFMA (~f32 accuracy). A: M x ~K row-major stride AS, guard KG.
// B: 300x300 f32 row-major stride BS. C: stride TSTR, cols >=300 get 0.
// Grid: (ceil(M/64), 5).
// ---------------------------------------------------------------------------
template <int BT, int BF16OUT>
__global__ __launch_bounds__(256) void k_gemm(const float* __restrict__ A,
                                              const float* __restrict__ B,
                                              void* __restrict__ Cout,
                                              int M, int AS, int BS, int KG) {
  __shared__ __align__(16) ushort arena[4 * L * S];   // 36.9 KB
  ushort* Ahi = arena;
  ushort* Alo = arena + L * S;
  ushort* Bhi = arena + 2 * L * S;
  ushort* Blo = arena + 3 * L * S;
  int mb = blockIdx.x, nb = blockIdx.y, tid = threadIdx.x;
  int lane = tid & 63, w = tid >> 6;
  int lrow = lane & 15, lk = lane >> 4;

  f32x4 acc[4];
  #pragma unroll
  for (int t = 0; t < 4; ++t) acc[t] = (f32x4){0.f, 0.f, 0.f, 0.f};

  for (int kc = 0; kc < 5; ++kc) {
    int k0 = 64 * kc;
    // stage A rows (hi/lo)
    for (int idx = tid; idx < 64 * 16; idx += 256) {
      int r = idx >> 4, c4 = (idx & 15) * 4;
      int m = mb * 64 + r, k = k0 + c4;
      float4 v = make_float4(0.f, 0.f, 0.f, 0.f);
      if (m < M && k < KG) v = *(const float4*)&A[(size_t)m * AS + k];
      ushort4 h4, l4;
      h4.x = f2b(v.x); l4.x = f2b(v.x - b2f(h4.x));
      h4.y = f2b(v.y); l4.y = f2b(v.y - b2f(h4.y));
      h4.z = f2b(v.z); l4.z = f2b(v.z - b2f(h4.z));
      h4.w = f2b(v.w); l4.w = f2b(v.w - b2f(h4.w));
      *(ushort4*)&Ahi[r * S + c4] = h4;
      *(ushort4*)&Alo[r * S + c4] = l4;
    }
    // stage B: frag[n_local][k_local] = (BT ? B[n][k] : B[k][n])
    for (int idx = tid; idx < 64 * 16; idx += 256) {
      int r = idx >> 4, c4 = (idx & 15) * 4;
      if (BT) {
        int n = nb * 64 + r, k = k0 + c4;
        float4 v = make_float4(0.f, 0.f, 0.f, 0.f);
        if (n < 300 && k < 300) v = *(const float4*)&B[(size_t)n * BS + k];
        ushort4 h4, l4;
        h4.x = f2b(v.x); l4.x = f2b(v.x - b2f(h4.x));
        h4.y = f2b(v.y); l4.y = f2b(v.y - b2f(h4.y));
        h4.z = f2b(v.z); l4.z = f2b(v.z - b2f(h4.z));
        h4.w = f2b(v.w); l4.w = f2b(v.w - b2f(h4.w));
        *(ushort4*)&Bhi[r * S + c4] = h4;
        *(ushort4*)&Blo[r * S + c4] = l4;
      } else {
        int k = k0 + r, n = nb * 64 + c4;
        float4 v = make_float4(0.f, 0.f, 0.f, 0.f);
        if (k < 300 && n < 300) v = *(const float4*)&B[(size_t)k * BS + n];
        #pragma unroll
        for (int q = 0; q < 4; ++q) {
          float xq = (q == 0) ? v.x : (q == 1) ? v.y : (q == 2) ? v.z : v.w;
          ushort hi = f2b(xq);
          Bhi[(size_t)(c4 + q) * S + r] = hi;
          Blo[(size_t)(c4 + q) * S + r] = f2b(xq - b2f(hi));
        }
      }
    }
    __syncthreads();
    #pragma unroll
    for (int ks = 0; ks < 2; ++ks) {
      bf16x8 ah = LD8(Ahi, 16 * w + lrow, 32 * ks + 8 * lk);
      bf16x8 al = LD8(Alo, 16 * w + lrow, 32 * ks + 8 * lk);
      #pragma unroll
      for (int t = 0; t < 4; ++t) {
        bf16x8 bh = LD8(Bhi, 16 * t + lrow, 32 * ks + 8 * lk);
        bf16x8 bl = LD8(Blo, 16 * t + lrow, 32 * ks + 8 * lk);
        acc[t] = MFMA(ah, bh, acc[t]);
        acc[t] = MFMA(ah, bl, acc[t]);
        acc[t] = MFMA(al, bh, acc[t]);
      }
    }
    __syncthreads();
  }
  #pragma unroll
  for (int t = 0; t < 4; ++t) {
    int n = nb * 64 + 16 * t + lrow;
    int mbase = mb * 64 + 16 * w + 4 * lk;
    if (n < TSTR) {
      #pragma unroll
      for (int r = 0; r < 4; ++r) {
        int m = mbase + r;
        if (m < M) {
          if (BF16OUT) ((ushort*)Cout)[(size_t)m * TSTR + n] = f2b(acc[t][r]);
          else         ((float*)Cout)[(size_t)m * TSTR + n] = acc[t][r];
        }
      }
    }
  }
}

// ---------------------------------------------------------------------------
// Fused per-batch kernel, all-MFMA, 2-buffer LDS (~20 KB -> 8 blocks/CU):
//   A  = norm(gather_u8 + I)       (255-scale cancels in normalization)
//   buf rows A -> reg frags -> buf A^T -> A2 -> buf A2^T -> A3 -> buf A3 rows
//   out[b]^T-tiles = T0g^T @ A3^T  (operand-swapped MFMA -> float4 stores)
// ---------------------------------------------------------------------------
__global__ __launch_bounds__(256, 8) void k_fused(const int* __restrict__ labels,
                                                  const unsigned char* __restrict__ adj8,
                                                  const ushort* __restrict__ t0bf,
                                                  float* __restrict__ out) {
  __shared__ __align__(16) ushort arena[2 * L * S];   // 18.4 KB
  ushort* buf0 = arena;
  ushort* buf1 = arena + L * S;
  __shared__ int   lab[L];
  __shared__ float ps[4][L];
  __shared__ float dv[L];

  int b = blockIdx.x, tid = threadIdx.x;
  int j = tid & 63, g = tid >> 6;
  if (tid < L) lab[tid] = labels[(size_t)b * L + tid];
  __syncthreads();
  int labj = lab[j];

  // gather raw counts (incl. 255*I) + fused column sums
  float raw[16];
  float cs = 0.f;
  #pragma unroll
  for (int q = 0; q < 16; ++q) {
    int i = g + 4 * q;
    float v = (float)adj8[(size_t)lab[i] * NN + labj];
    v += (i == j) ? 255.f : 0.f;
    raw[q] = v; cs += v;
  }
  ps[g][j] = cs;
  __syncthreads();
  if (tid < L) dv[tid] = 1.f / sqrtf(ps[0][tid] + ps[1][tid] + ps[2][tid] + ps[3][tid]);
  __syncthreads();

  // scale in regs; write A rows (hi/lo) into buf0/buf1
  float dj = dv[j];
  #pragma unroll
  for (int q = 0; q < 16; ++q) {
    int i = g + 4 * q;
    float a = raw[q] * dv[i] * dj;
    raw[q] = a;                        // keep scaled value for the A^T pass
    ushort hi = f2b(a);
    buf0[(size_t)i * S + j] = hi;
    buf1[(size_t)i * S + j] = f2b(a - b2f(hi));
  }
  __syncthreads();

  int lane = tid & 63, w = tid >> 6;
  int lrow = lane & 15, lk = lane >> 4;
  int m0 = 16 * w;

  // A-side register fragments of A rows (reused for A^2 and A^3)
  bf16x8 ah0 = LD8(buf0, m0 + lrow, 8 * lk);
  bf16x8 ah1 = LD8(buf0, m0 + lrow, 32 + 8 * lk);
  bf16x8 al0 = LD8(buf1, m0 + lrow, 8 * lk);
  bf16x8 al1 = LD8(buf1, m0 + lrow, 32 + 8 * lk);
  __syncthreads();   // frag reads done; buffers reusable

  // overwrite buf0/buf1 with A^T (hi/lo) from the scaled regs
  #pragma unroll
  for (int q = 0; q < 16; ++q) {
    int i = g + 4 * q;
    float a = raw[q];
    ushort hi = f2b(a);
    buf0[(size_t)j * S + i] = hi;
    buf1[(size_t)j * S + i] = f2b(a - b2f(hi));
  }
  __syncthreads();

  // ---- A2 = A @ A  (3-term hi/lo) -> overwrite buf0/1 with A2^T ----
  {
    f32x4 acc[4];
    #pragma unroll
    for (int t = 0; t < 4; ++t) {
      f32x4 a = {0.f, 0.f, 0.f, 0.f};
      bf16x8 bh = LD8(buf0, 16 * t + lrow, 8 * lk);
      bf16x8 bl = LD8(buf1, 16 * t + lrow, 8 * lk);
      a = MFMA(ah0, bh, a); a = MFMA(ah0, bl, a); a = MFMA(al0, bh, a);
      bh = LD8(buf0, 16 * t + lrow, 32 + 8 * lk);
      bl = LD8(buf1, 16 * t + lrow, 32 + 8 * lk);
      a = MFMA(ah1, bh, a); a = MFMA(ah1, bl, a); a = MFMA(al1, bh, a);
      acc[t] = a;
    }
    __syncthreads();   // all reads done
    #pragma unroll
    for (int t = 0; t < 4; ++t) {
      ushort4 h4, l4;
      float x;
      x = acc[t][0]; h4.x = f2b(x); l4.x = f2b(x - b2f(h4.x));
      x = acc[t][1]; h4.y = f2b(x); l4.y = f2b(x - b2f(h4.y));
      x = acc[t][2]; h4.z = f2b(x); l4.z = f2b(x - b2f(h4.z));
      x = acc[t][3]; h4.w = f2b(x); l4.w = f2b(x - b2f(h4.w));
      // acc[t][r] = A2[m0+4lk+r][16t+lrow]  ->  A2T[16t+lrow][m0+4lk+r]
      *(ushort4*)&buf0[(size_t)(16 * t + lrow) * S + m0 + 4 * lk] = h4;
      *(ushort4*)&buf1[(size_t)(16 * t + lrow) * S + m0 + 4 * lk] = l4;
    }
  }
  __syncthreads();

  // ---- A3 = A @ A2  (3-term) -> overwrite buf0 with A3 rows (bf16) ----
  {
    f32x4 acc[4];
    #pragma unroll
    for (int t = 0; t < 4; ++t) {
      f32x4 a = {0.f, 0.f, 0.f, 0.f};
      bf16x8 bh = LD8(buf0, 16 * t + lrow, 8 * lk);
      bf16x8 bl = LD8(buf1, 16 * t + lrow, 8 * lk);
      a = MFMA(ah0, bh, a); a = MFMA(ah0, bl, a); a = MFMA(al0, bh, a);
      bh = LD8(buf0, 16 * t + lrow, 32 + 8 * lk);
      bl = LD8(buf1, 16 * t + lrow, 32 + 8 * lk);
      a = MFMA(ah1, bh, a); a = MFMA(ah1, bl, a); a = MFMA(al1, bh, a);
      acc[t] = a;
    }
    __syncthreads();   // all reads done
    #pragma unroll
    for (int t = 0; t < 4; ++t)
      #pragma unroll
      for (int r = 0; r < 4; ++r)
        buf0[(size_t)(m0 + 4 * lk + r) * S + 16 * t + lrow] = f2b(acc[t][r]);
  }
  __syncthreads();

  // ---- out^T-tiles = T0g^T @ A3^T  (swapped operands -> float4 stores) ----
  bf16x8 fb0 = LD8(buf0, m0 + lrow, 8 * lk);
  bf16x8 fb1 = LD8(buf0, m0 + lrow, 32 + 8 * lk);
  __syncthreads();   // fb frag reads done; whole arena free for Tt
  ushort* Tt = arena;                      // [80][S] = 11.5 KB < 18.4 KB
  const ushort* trow = t0bf + (size_t)labj * TSTR;
  float* orow = out + ((size_t)b * L + m0 + lrow) * EMB;  // this lane's row

  for (int c = 0; c < 4; ++c) {
    int rows80 = (c == 3) ? 64 : 80;
    for (int e = 8 * g; e < rows80; e += 32) {
      union { int4 v; ushort u[8]; } uu;
      uu.v = *(const int4*)(trow + 80 * c + e);
      #pragma unroll
      for (int q = 0; q < 8; ++q) Tt[(size_t)(e + q) * S + j] = uu.u[q];
    }
    __syncthreads();
    int nt = (c == 3) ? 4 : 5;
    for (int t = 0; t < nt; ++t) {
      bf16x8 a0 = LD8(Tt, 16 * t + lrow, 8 * lk);
      bf16x8 a1 = LD8(Tt, 16 * t + lrow, 32 + 8 * lk);
      f32x4 o = {0.f, 0.f, 0.f, 0.f};
      o = MFMA(a0, fb0, o);
      o = MFMA(a1, fb1, o);
      int e0 = 80 * c + 16 * t + 4 * lk;
      if (e0 < EMB) {
        *(f32x4*)&orow[e0] = o;
      }
    }
    __syncthreads();
  }
}

// ---------------------------------------------------------------------------
extern "C" void kernel_launch(void* const* d_in, const int* in_sizes, int n_in,
                              void* d_out, int out_size, void* d_ws, size_t ws_size,
                              hipStream_t stream) {
  (void)in_sizes; (void)n_in; (void)out_size; (void)ws_size;
  const int*   labels = (const int*)d_in[0];
  const float* in_adj = (const float*)d_in[1];
  const float* emb    = (const float*)d_in[2];
  const float* lw     = (const float*)d_in[3];
  float* out = (float*)d_out;

  char* base = (char*)d_ws;
  unsigned char* adj8 = (unsigned char*)base;            // 2,563,201 B
  float*  T    = (float*)(base + 2563216);               // 300x304 f32
  float*  Wc   = (float*)(base + 2563216 + 364800);      // 300x304 f32
  ushort* t0bf = (ushort*)(base + 2563216 + 729600);     // 1601x304 bf16

  const float* W1 = lw;
  const float* W2 = lw + (size_t)EMB * EMB;
  const float* W3 = lw + 2 * (size_t)EMB * EMB;

  k_u8<<<1024, 256, 0, stream>>>(in_adj, adj8);

  dim3 gsm(5, 5), gbig(26, 5);
  k_gemm<0, 0><<<gsm, 256, 0, stream>>>(W3, W2, T, 300, 300, 300, 300);   // T  = W3@W2
  k_gemm<0, 0><<<gsm, 256, 0, stream>>>(T, W1, Wc, 300, TSTR, 300, 300);  // Wc = T@W1
  k_gemm<1, 1><<<gbig, 256, 0, stream>>>(emb, Wc, t0bf, NN, 300, TSTR, 300); // t0 = emb@Wc^T

  k_fused<<<NB, 256, 0, stream>>>(labels, adj8, t0bf, out);
}

// Round 10
// 108.888 us; speedup vs baseline: 2.0024x; 1.0757x over previous
//
#include <hip/hip_runtime.h>

#define NN   1601
#define EMB  300
#define NB   2048
#define L    64
#define TSTR 304   // t0bf / T / E1 row stride (elements)
#define S    72    // LDS matrix stride (u16) -> 144B rows, 16B-aligned frags

typedef __attribute__((ext_vector_type(8))) short bf16x8;
typedef __attribute__((ext_vector_type(4))) float f32x4;

static __device__ __forceinline__ ushort f2b(float x) {
  union { float f; unsigned u; } c; c.f = x;
  unsigned u = c.u;
  return (ushort)((u + 0x7FFFu + ((u >> 16) & 1u)) >> 16);   // RNE
}
static __device__ __forceinline__ float b2f(ushort h) {
  union { unsigned u; float f; } c; c.u = ((unsigned)h) << 16; return c.f;
}

#define LD8(p, r, c) (*(const bf16x8*)&(p)[(size_t)(r) * S + (c)])
#define MFMA(a, bm, acc) __builtin_amdgcn_mfma_f32_16x16x32_bf16((a), (bm), (acc), 0, 0, 0)

// ---------------------------------------------------------------------------
// GEMM body: C(. x TSTR-stride) = A @ B^T (BT=1) or A @ B (BT=0), hi/lo bf16
// 3-term MFMA (~f32). A: stride AS, K-guard KG. B: 300x300, stride BS.
// C cols >= 300 get 0. One 64x64 tile per call (mb, nb).
// ---------------------------------------------------------------------------
template <int BT, int BF16OUT>
__device__ __forceinline__ void gemm_body(ushort* arena,
                                          const float* __restrict__ A,
                                          const float* __restrict__ B,
                                          void* __restrict__ Cout,
                                          int M, int AS, int BS, int KG,
                                          int mb, int nb) {
  ushort* Ahi = arena;
  ushort* Alo = arena + L * S;
  ushort* Bhi = arena + 2 * L * S;
  ushort* Blo = arena + 3 * L * S;
  int tid = threadIdx.x;
  int lane = tid & 63, w = tid >> 6;
  int lrow = lane & 15, lk = lane >> 4;

  f32x4 acc[4];
  #pragma unroll
  for (int t = 0; t < 4; ++t) acc[t] = (f32x4){0.f, 0.f, 0.f, 0.f};

  for (int kc = 0; kc < 5; ++kc) {
    int k0 = 64 * kc;
    for (int idx = tid; idx < 64 * 16; idx += 256) {
      int r = idx >> 4, c4 = (idx & 15) * 4;
      int m = mb * 64 + r, k = k0 + c4;
      float4 v = make_float4(0.f, 0.f, 0.f, 0.f);
      if (m < M && k < KG) v = *(const float4*)&A[(size_t)m * AS + k];
      ushort4 h4, l4;
      h4.x = f2b(v.x); l4.x = f2b(v.x - b2f(h4.x));
      h4.y = f2b(v.y); l4.y = f2b(v.y - b2f(h4.y));
      h4.z = f2b(v.z); l4.z = f2b(v.z - b2f(h4.z));
      h4.w = f2b(v.w); l4.w = f2b(v.w - b2f(h4.w));
      *(ushort4*)&Ahi[r * S + c4] = h4;
      *(ushort4*)&Alo[r * S + c4] = l4;
    }
    for (int idx = tid; idx < 64 * 16; idx += 256) {
      int r = idx >> 4, c4 = (idx & 15) * 4;
      if (BT) {
        int n = nb * 64 + r, k = k0 + c4;
        float4 v = make_float4(0.f, 0.f, 0.f, 0.f);
        if (n < 300 && k < 300) v = *(const float4*)&B[(size_t)n * BS + k];
        ushort4 h4, l4;
        h4.x = f2b(v.x); l4.x = f2b(v.x - b2f(h4.x));
        h4.y = f2b(v.y); l4.y = f2b(v.y - b2f(h4.y));
        h4.z = f2b(v.z); l4.z = f2b(v.z - b2f(h4.z));
        h4.w = f2b(v.w); l4.w = f2b(v.w - b2f(h4.w));
        *(ushort4*)&Bhi[r * S + c4] = h4;
        *(ushort4*)&Blo[r * S + c4] = l4;
      } else {
        int k = k0 + r, n = nb * 64 + c4;
        float4 v = make_float4(0.f, 0.f, 0.f, 0.f);
        if (k < 300 && n < 300) v = *(const float4*)&B[(size_t)k * BS + n];
        #pragma unroll
        for (int q = 0; q < 4; ++q) {
          float xq = (q == 0) ? v.x : (q == 1) ? v.y : (q == 2) ? v.z : v.w;
          ushort hi = f2b(xq);
          Bhi[(size_t)(c4 + q) * S + r] = hi;
          Blo[(size_t)(c4 + q) * S + r] = f2b(xq - b2f(hi));
        }
      }
    }
    __syncthreads();
    #pragma unroll
    for (int ks = 0; ks < 2; ++ks) {
      bf16x8 ah = LD8(Ahi, 16 * w + lrow, 32 * ks + 8 * lk);
      bf16x8 al = LD8(Alo, 16 * w + lrow, 32 * ks + 8 * lk);
      #pragma unroll
      for (int t = 0; t < 4; ++t) {
        bf16x8 bh = LD8(Bhi, 16 * t + lrow, 32 * ks + 8 * lk);
        bf16x8 bl = LD8(Blo, 16 * t + lrow, 32 * ks + 8 * lk);
        acc[t] = MFMA(ah, bh, acc[t]);
        acc[t] = MFMA(ah, bl, acc[t]);
        acc[t] = MFMA(al, bh, acc[t]);
      }
    }
    __syncthreads();
  }
  #pragma unroll
  for (int t = 0; t < 4; ++t) {
    int n = nb * 64 + 16 * t + lrow;
    int mbase = mb * 64 + 16 * w + 4 * lk;
    if (n < TSTR) {
      #pragma unroll
      for (int r = 0; r < 4; ++r) {
        int m = mbase + r;
        if (m < M) {
          if (BF16OUT) ((ushort*)Cout)[(size_t)m * TSTR + n] = f2b(acc[t][r]);
          else         ((float*)Cout)[(size_t)m * TSTR + n] = acc[t][r];
        }
      }
    }
  }
}

// ---------------------------------------------------------------------------
// Launch 1: [0,25) T = W3@W2 | [25,155) E1 = emb@W1^T | [155,1179) u8 quant
// ---------------------------------------------------------------------------
__global__ __launch_bounds__(256, 4) void k_pre1(const float* __restrict__ in_adj,
                                                 unsigned char* __restrict__ adj8,
                                                 const float* __restrict__ emb,
                                                 const float* __restrict__ lw,
                                                 float* __restrict__ E1,
                                                 float* __restrict__ T) {
  __shared__ __align__(16) ushort arena[4 * L * S];
  const float* W1 = lw;
  const float* W2 = lw + (size_t)EMB * EMB;
  const float* W3 = lw + 2 * (size_t)EMB * EMB;
  int bid = blockIdx.x;
  if (bid < 25) {
    gemm_body<0, 0>(arena, W3, W2, T, 300, 300, 300, 300, bid / 5, bid % 5);
  } else if (bid < 155) {
    int rid = bid - 25;
    gemm_body<1, 0>(arena, emb, W1, E1, NN, 300, 300, 300, rid % 26, rid / 26);
  } else {
    int b2 = bid - 155;
    const int total = NN * NN;           // 2563201
    const int n4 = total >> 2;
    int i = b2 * 256 + threadIdx.x;
    for (int i4 = i; i4 < n4; i4 += 1024 * 256) {
      float4 v = *(const float4*)&in_adj[4 * i4];
      uchar4 q;
      q.x = (unsigned char)__float2int_rn(v.x * 255.f);
      q.y = (unsigned char)__float2int_rn(v.y * 255.f);
      q.z = (unsigned char)__float2int_rn(v.z * 255.f);
      q.w = (unsigned char)__float2int_rn(v.w * 255.f);
      *(uchar4*)&adj8[4 * i4] = q;
    }
    if (i == 0)
      adj8[total - 1] = (unsigned char)__float2int_rn(in_adj[total - 1] * 255.f);
  }
}

// ---------------------------------------------------------------------------
// A^3 body: A = norm(gather_u8 + I); A2 = A@A; A3 = A@A2 (hi/lo 3-term MFMA),
// writes A3 as 64x64 bf16 row-major to a3g[b].
// ---------------------------------------------------------------------------
__device__ __forceinline__ void a3_body(ushort* arena, int* lab, float (*ps)[L],
                                        float* dv, const int* __restrict__ labels,
                                        const unsigned char* __restrict__ adj8,
                                        ushort* __restrict__ a3g, int b) {
  ushort* buf0 = arena;              // A rows hi -> A3 rows
  ushort* buf1 = arena + L * S;      // A rows lo
  ushort* buf2 = arena + 2 * L * S;  // A^T hi -> A2^T hi
  ushort* buf3 = arena + 3 * L * S;  // A^T lo -> A2^T lo
  int tid = threadIdx.x, j = tid & 63, g = tid >> 6;
  if (tid < L) lab[tid] = labels[(size_t)b * L + tid];
  __syncthreads();
  int labj = lab[j];

  float raw[16];
  float cs = 0.f;
  #pragma unroll
  for (int q = 0; q < 16; ++q) {
    int i = g + 4 * q;
    float v = (float)adj8[(size_t)lab[i] * NN + labj];
    v += (i == j) ? 255.f : 0.f;
    raw[q] = v; cs += v;
  }
  ps[g][j] = cs;
  __syncthreads();
  if (tid < L) dv[tid] = 1.f / sqrtf(ps[0][tid] + ps[1][tid] + ps[2][tid] + ps[3][tid]);
  __syncthreads();

  float dj = dv[j];
  #pragma unroll
  for (int q = 0; q < 16; ++q) {
    int i = g + 4 * q;
    float a = raw[q] * dv[i] * dj;
    ushort hi = f2b(a);
    ushort lo = f2b(a - b2f(hi));
    buf0[(size_t)i * S + j] = hi;
    buf1[(size_t)i * S + j] = lo;
    buf2[(size_t)j * S + i] = hi;
    buf3[(size_t)j * S + i] = lo;
  }
  __syncthreads();

  int lane = tid & 63, w = tid >> 6;
  int lrow = lane & 15, lk = lane >> 4;
  int m0 = 16 * w;

  bf16x8 ah0 = LD8(buf0, m0 + lrow, 8 * lk);
  bf16x8 ah1 = LD8(buf0, m0 + lrow, 32 + 8 * lk);
  bf16x8 al0 = LD8(buf1, m0 + lrow, 8 * lk);
  bf16x8 al1 = LD8(buf1, m0 + lrow, 32 + 8 * lk);

  // A2 = A @ A -> A2^T into buf2/buf3
  {
    f32x4 acc[4];
    #pragma unroll
    for (int t = 0; t < 4; ++t) {
      f32x4 a = {0.f, 0.f, 0.f, 0.f};
      bf16x8 bh = LD8(buf2, 16 * t + lrow, 8 * lk);
      bf16x8 bl = LD8(buf3, 16 * t + lrow, 8 * lk);
      a = MFMA(ah0, bh, a); a = MFMA(ah0, bl, a); a = MFMA(al0, bh, a);
      bh = LD8(buf2, 16 * t + lrow, 32 + 8 * lk);
      bl = LD8(buf3, 16 * t + lrow, 32 + 8 * lk);
      a = MFMA(ah1, bh, a); a = MFMA(ah1, bl, a); a = MFMA(al1, bh, a);
      acc[t] = a;
    }
    __syncthreads();
    #pragma unroll
    for (int t = 0; t < 4; ++t) {
      ushort4 h4, l4;
      float x;
      x = acc[t][0]; h4.x = f2b(x); l4.x = f2b(x - b2f(h4.x));
      x = acc[t][1]; h4.y = f2b(x); l4.y = f2b(x - b2f(h4.y));
      x = acc[t][2]; h4.z = f2b(x); l4.z = f2b(x - b2f(h4.z));
      x = acc[t][3]; h4.w = f2b(x); l4.w = f2b(x - b2f(h4.w));
      *(ushort4*)&buf2[(size_t)(16 * t + lrow) * S + m0 + 4 * lk] = h4;
      *(ushort4*)&buf3[(size_t)(16 * t + lrow) * S + m0 + 4 * lk] = l4;
    }
  }
  __syncthreads();

  // A3 = A @ A2 -> rows into buf0
  {
    f32x4 acc[4];
    #pragma unroll
    for (int t = 0; t < 4; ++t) {
      f32x4 a = {0.f, 0.f, 0.f, 0.f};
      bf16x8 bh = LD8(buf2, 16 * t + lrow, 8 * lk);
      bf16x8 bl = LD8(buf3, 16 * t + lrow, 8 * lk);
      a = MFMA(ah0, bh, a); a = MFMA(ah0, bl, a); a = MFMA(al0, bh, a);
      bh = LD8(buf2, 16 * t + lrow, 32 + 8 * lk);
      bl = LD8(buf3, 16 * t + lrow, 32 + 8 * lk);
      a = MFMA(ah1, bh, a); a = MFMA(ah1, bl, a); a = MFMA(al1, bh, a);
      acc[t] = a;
    }
    #pragma unroll
    for (int t = 0; t < 4; ++t)
      #pragma unroll
      for (int r = 0; r < 4; ++r)
        buf0[(size_t)(m0 + 4 * lk + r) * S + 16 * t + lrow] = f2b(acc[t][r]);
  }
  __syncthreads();

  // coalesced store: a3g[b] = 64x64 bf16 row-major (8 KB)
  int4* dst = (int4*)(a3g + (size_t)b * (L * L));
  #pragma unroll
  for (int q = 0; q < 2; ++q) {
    int id = tid + 256 * q;
    int r = id >> 3, c8 = (id & 7) << 3;
    dst[id] = *(const int4*)&buf0[(size_t)r * S + c8];
  }
}

// ---------------------------------------------------------------------------
// Launch 2: [0,2048) A^3 | [2048,2178) t0bf = E1 @ T^T (bf16 out)
// ---------------------------------------------------------------------------
__global__ __launch_bounds__(256, 4) void k_pre2(const int* __restrict__ labels,
                                                 const unsigned char* __restrict__ adj8,
                                                 ushort* __restrict__ a3g,
                                                 const float* __restrict__ E1,
                                                 const float* __restrict__ T,
                                                 ushort* __restrict__ t0bf) {
  __shared__ __align__(16) ushort arena[4 * L * S];
  __shared__ int   lab[L];
  __shared__ float ps[4][L];
  __shared__ float dv[L];
  int bid = blockIdx.x;
  if (bid < NB) {
    a3_body(arena, lab, ps, dv, labels, adj8, a3g, bid);
  } else {
    int rid = bid - NB;
    gemm_body<1, 1>(arena, E1, T, t0bf, NN, TSTR, TSTR, TSTR, rid % 26, rid / 26);
  }
}

// ---------------------------------------------------------------------------
// Launch 3: out tiles. grid 8192: b = bid>>2, e-chunk c = bid&3.
// Stage A3[b] (8 KB coalesced) + Tt chunk, 1 barrier, MFMA, f32x4 stores.
// ---------------------------------------------------------------------------
__global__ __launch_bounds__(256, 6) void k_out(const int* __restrict__ labels,
                                                const ushort* __restrict__ a3g,
                                                const ushort* __restrict__ t0bf,
                                                float* __restrict__ out) {
  __shared__ __align__(16) ushort A3L[L * S];    // 9216 B
  __shared__ __align__(16) ushort Tt[80 * S];    // 11520 B
  int bid = blockIdx.x;
  int b = bid >> 2, c = bid & 3;
  int tid = threadIdx.x, j = tid & 63, g = tid >> 6;
  int labj = labels[(size_t)b * L + j];

  // stage A3 rows (coalesced int4)
  const int4* a3p = (const int4*)(a3g + (size_t)b * (L * L));
  #pragma unroll
  for (int q = 0; q < 2; ++q) {
    int id = tid + 256 * q;
    int r = id >> 3, c8 = (id & 7) << 3;
    *(int4*)&A3L[(size_t)r * S + c8] = a3p[id];
  }
  // stage Tt[e_local][j] = t0bf[lab[j]][80c + e_local]
  int base = 80 * c;
  int rows80 = (c == 3) ? 64 : 80;
  const ushort* trow = t0bf + (size_t)labj * TSTR + base;
  for (int e = 8 * g; e < rows80; e += 32) {
    union { int4 v; ushort u[8]; } uu;
    uu.v = *(const int4*)(trow + e);
    #pragma unroll
    for (int q = 0; q < 8; ++q) Tt[(size_t)(e + q) * S + j] = uu.u[q];
  }
  __syncthreads();

  int lane = tid & 63, w = tid >> 6;
  int lrow = lane & 15, lk = lane >> 4;
  int m0 = 16 * w;
  bf16x8 fb0 = LD8(A3L, m0 + lrow, 8 * lk);
  bf16x8 fb1 = LD8(A3L, m0 + lrow, 32 + 8 * lk);
  float* orow = out + ((size_t)b * L + m0 + lrow) * EMB;

  int nt = (c == 3) ? 4 : 5;
  for (int t = 0; t < nt; ++t) {
    bf16x8 a0 = LD8(Tt, 16 * t + lrow, 8 * lk);
    bf16x8 a1 = LD8(Tt, 16 * t + lrow, 32 + 8 * lk);
    f32x4 o = {0.f, 0.f, 0.f, 0.f};
    o = MFMA(a0, fb0, o);
    o = MFMA(a1, fb1, o);
    int e0 = base + 16 * t + 4 * lk;
    if (e0 < EMB) *(f32x4*)&orow[e0] = o;
  }
}

// ---------------------------------------------------------------------------
extern "C" void kernel_launch(void* const* d_in, const int* in_sizes, int n_in,
                              void* d_out, int out_size, void* d_ws, size_t ws_size,
                              hipStream_t stream) {
  (void)in_sizes; (void)n_in; (void)out_size; (void)ws_size;
  const int*   labels = (const int*)d_in[0];
  const float* in_adj = (const float*)d_in[1];
  const float* emb    = (const float*)d_in[2];
  const float* lw     = (const float*)d_in[3];
  float* out = (float*)d_out;

  char* base = (char*)d_ws;
  unsigned char* adj8 = (unsigned char*)base;              // 2,563,201 B
  float*  T    = (float*)(base + 2563216);                 // 300x304 f32
  float*  E1   = (float*)(base + 2928016);                 // 1601x304 f32
  ushort* t0bf = (ushort*)(base + 4874832);                // 1601x304 bf16
  ushort* a3g  = (ushort*)(base + 5848240);                // 2048x64x64 bf16

  k_pre1<<<1179, 256, 0, stream>>>(in_adj, adj8, emb, lw, E1, T);
  k_pre2<<<2178, 256, 0, stream>>>(labels, adj8, a3g, E1, T, t0bf);
  k_out <<<4 * NB, 256, 0, stream>>>(labels, a3g, t0bf, out);
}